// Round 6
// baseline (174.136 us; speedup 1.0000x reference)
//
#include <hip/hip_runtime.h>
#include <hip/hip_bf16.h>
#include <stdint.h>

#define B_    4
#define NN    4096
#define DIN   512
#define DOUT  256
#define ALPHA_ 0.2f

typedef __attribute__((ext_vector_type(8))) short short8;
typedef __attribute__((ext_vector_type(4))) float f32x4;

typedef const __attribute__((address_space(1))) void gconst_void;
typedef __attribute__((address_space(3))) void lds_void;

__device__ __forceinline__ unsigned short f2bf(float x) {
    union { float f; uint32_t u; } v; v.f = x;
    uint32_t r = v.u + 0x7FFFu + ((v.u >> 16) & 1u);
    return (unsigned short)(r >> 16);
}

// ---------------- K_prep: pack adj -> bits | h fp32->bf16 | Ws -> WsT bf16 ----------
__global__ __launch_bounds__(256) void k_prep(const int* __restrict__ adj,
                                              const float4* __restrict__ h4,
                                              const float* __restrict__ Ws,
                                              uint32_t* __restrict__ bits,
                                              uint2* __restrict__ hb,
                                              unsigned short* __restrict__ wst) {
    const int gid = blockIdx.x;
    const int tid = threadIdx.x;
    if (gid < 65536) {                       // pack adj: 67MB -> 2MB
        int idx = gid * 256 + tid;
        unsigned long long m = __ballot(adj[idx] > 0);
        if ((tid & 63) == 0)
            *reinterpret_cast<unsigned long long*>(bits + ((idx >> 6) << 1)) = m;
    } else if (gid < 73728) {                // h -> bf16 (float4 granularity)
        int idx = (gid - 65536) * 256 + tid;
        float4 v = h4[idx];
        uint2 o;
        o.x = (uint32_t)f2bf(v.x) | ((uint32_t)f2bf(v.y) << 16);
        o.y = (uint32_t)f2bf(v.z) | ((uint32_t)f2bf(v.w) << 16);
        hb[idx] = o;
    } else {                                 // Ws (B,DIN,DOUT) -> WsT (B,DOUT,DIN)
        int idx = (gid - 73728) * 256 + tid;
        int k = idx & (DIN - 1);
        int o = (idx >> 9) & (DOUT - 1);
        int b = idx >> 17;
        wst[idx] = f2bf(Ws[((size_t)b * DIN + k) * DOUT + o]);
    }
}

// ---------------- K1: WhT[b][d][m] = (h @ Ws)^T + fused e1/e2 epilogue --------------
__global__ __launch_bounds__(256) void k_gemm1(const unsigned short* __restrict__ hb,
                                               const unsigned short* __restrict__ wst,
                                               const float* __restrict__ a,
                                               unsigned short* __restrict__ wht,
                                               float* __restrict__ e1,
                                               float* __restrict__ e2) {
    __shared__ unsigned short Ah[64 * 64];    // [n][k] swizzled rows (128B)
    __shared__ unsigned short Bw[256 * 64];   // [d][k] swizzled rows (128B)
    __shared__ float e1s[64], e2s[64];
    const int tid = threadIdx.x;
    const int w = tid >> 6, lane = tid & 63;
    const int l15 = lane & 15, lhi = lane >> 4;
    const int b = blockIdx.y;
    const int n0 = blockIdx.x * 64;
    const unsigned short* hrow = hb + ((size_t)b * NN + n0) * DIN;
    const unsigned short* wrow = wst + (size_t)b * DOUT * DIN;

    if (tid < 64) { e1s[tid] = 0.f; e2s[tid] = 0.f; }

    f32x4 acc[4][4] = {};

    for (int kt = 0; kt < DIN / 64; ++kt) {
        const int k0 = kt * 64;
        #pragma unroll
        for (int it = 0; it < 2; ++it) {     // stage A: 8KB
            int q = it * 256 + tid;
            int row = q >> 3, c = q & 7;
            const unsigned short* src = hrow + (size_t)row * DIN + k0 + 8 * (c ^ (row & 7));
            char* dst = reinterpret_cast<char*>(Ah) + it * 4096 + w * 1024;
            __builtin_amdgcn_global_load_lds((gconst_void*)src, (lds_void*)dst, 16, 0, 0);
        }
        #pragma unroll
        for (int it = 0; it < 8; ++it) {     // stage B: 32KB
            int q = it * 256 + tid;
            int row = q >> 3, c = q & 7;
            const unsigned short* src = wrow + (size_t)row * DIN + k0 + 8 * (c ^ (row & 7));
            char* dst = reinterpret_cast<char*>(Bw) + it * 4096 + w * 1024;
            __builtin_amdgcn_global_load_lds((gconst_void*)src, (lds_void*)dst, 16, 0, 0);
        }
        __syncthreads();
        #pragma unroll
        for (int kk = 0; kk < 2; ++kk) {
            short8 af[4], bfr[4];
            #pragma unroll
            for (int rf = 0; rf < 4; ++rf) {
                int row = rf * 16 + l15;
                int off = row * 128 + ((kk * 64 + lhi * 16) ^ ((row & 7) << 4));
                af[rf] = *reinterpret_cast<const short8*>(reinterpret_cast<const char*>(Ah) + off);
            }
            #pragma unroll
            for (int cf = 0; cf < 4; ++cf) {
                int row = w * 64 + cf * 16 + l15;
                int off = row * 128 + ((kk * 64 + lhi * 16) ^ ((row & 7) << 4));
                bfr[cf] = *reinterpret_cast<const short8*>(reinterpret_cast<const char*>(Bw) + off);
            }
            #pragma unroll
            for (int rf = 0; rf < 4; ++rf)
                #pragma unroll
                for (int cf = 0; cf < 4; ++cf)
                    acc[rf][cf] = __builtin_amdgcn_mfma_f32_16x16x32_bf16(af[rf], bfr[cf], acc[rf][cf], 0, 0, 0);
        }
        __syncthreads();
    }
    // WhT write (bf16, transposed)
    unsigned short* wb = wht + (size_t)b * DOUT * NN;
    #pragma unroll
    for (int rf = 0; rf < 4; ++rf) {
        #pragma unroll
        for (int cf = 0; cf < 4; ++cf) {
            int d = w * 64 + cf * 16 + l15;
            int m = n0 + rf * 16 + lhi * 4;
            uint2 pk;
            pk.x = (uint32_t)f2bf(acc[rf][cf][0]) | ((uint32_t)f2bf(acc[rf][cf][1]) << 16);
            pk.y = (uint32_t)f2bf(acc[rf][cf][2]) | ((uint32_t)f2bf(acc[rf][cf][3]) << 16);
            *reinterpret_cast<uint2*>(wb + (size_t)d * NN + m) = pk;
        }
    }
    // fused e1/e2 via shfl-reduce over the 16-lane fragment columns
    const float* ab = a + b * 2 * DOUT;
    float a1v[4], a2v[4];
    #pragma unroll
    for (int cf = 0; cf < 4; ++cf) {
        int d = w * 64 + cf * 16 + l15;
        a1v[cf] = ab[d];
        a2v[cf] = ab[DOUT + d];
    }
    #pragma unroll
    for (int rf = 0; rf < 4; ++rf) {
        #pragma unroll
        for (int j = 0; j < 4; ++j) {
            float p1 = 0.f, p2 = 0.f;
            #pragma unroll
            for (int cf = 0; cf < 4; ++cf) {
                p1 = fmaf(acc[rf][cf][j], a1v[cf], p1);
                p2 = fmaf(acc[rf][cf][j], a2v[cf], p2);
            }
            #pragma unroll
            for (int msk = 1; msk < 16; msk <<= 1) {
                p1 += __shfl_xor(p1, msk);
                p2 += __shfl_xor(p2, msk);
            }
            if (l15 == 0) {
                atomicAdd(&e1s[rf * 16 + lhi * 4 + j], p1);
                atomicAdd(&e2s[rf * 16 + lhi * 4 + j], p2);
            }
        }
    }
    __syncthreads();
    if (tid < 64) {
        e1[b * NN + n0 + tid] = e1s[tid];
        e2[b * NN + n0 + tid] = e2s[tid];
    }
}

// ---------------- K4: h' = softmax(P)@Wh, in-register P + ones-column row-sum ------
// block 64n x 128d, 4 waves (wn2 x wd2) each 32n x 64d. LDS = Bw dbuf only (32KB).
// Each lane computes P directly into its MFMA A-fragments (no Pt LDS round-trip);
// row-sums accumulate via an extra MFMA against a constant ones B-fragment.
__global__ __launch_bounds__(256, 2) void k_attn(const unsigned short* __restrict__ wht,
                                                 const uint32_t* __restrict__ bits,
                                                 const float* __restrict__ e1,
                                                 const float* __restrict__ e2,
                                                 float* __restrict__ out) {
    __shared__ unsigned short Bw[2 * 128 * 64];  // WhT tile dbuf, swizzled rows (32KB)

    const int tid = threadIdx.x;
    const int w = tid >> 6, lane = tid & 63;
    const int l15 = lane & 15, lh4 = lane >> 4;
    const int wn = w >> 1, wd = w & 1;

    // XCD-aware bijective swizzle: 512 blocks
    const int bid = blockIdx.x;
    const int wg = ((bid & 7) << 6) | (bid >> 3);
    const int b  = wg >> 7;
    const int r  = wg & 127;
    const int d0 = (r & 1) << 7;
    const int n0 = (r >> 1) << 6;

    const int gn = n0 + wn * 32 + l15;           // rf=0 row; rf=1 -> +16
    const float r1a = e1[b * NN + gn];
    const float r1b = e1[b * NN + gn + 16];
    const float r2a = ALPHA_ * r1a, r2b = ALPHA_ * r1b;
    const unsigned long long* bra =
        reinterpret_cast<const unsigned long long*>(bits + (size_t)gn * (NN / 32));
    const unsigned long long* brb =
        reinterpret_cast<const unsigned long long*>(bits + (size_t)(gn + 16) * (NN / 32));
    const float* e2g = e2 + b * NN;
    const unsigned short* wb = wht + (size_t)b * DOUT * NN;

    f32x4 acc[2][4] = {};
    f32x4 accs[2] = {};
    short8 ones;
    {
        union { short8 v; uint32_t u[4]; } ov;
        ov.u[0] = 0x3F803F80u; ov.u[1] = 0x3F803F80u;
        ov.u[2] = 0x3F803F80u; ov.u[3] = 0x3F803F80u;
        ones = ov.v;
    }
    short8 afA[2][2], afB[2][2];

#define STAGE(T, BUF)                                                                  \
    {                                                                                  \
        _Pragma("unroll")                                                              \
        for (int it = 0; it < 4; ++it) {                                               \
            int q = it * 256 + tid;                                                    \
            int row = q >> 3, c = q & 7;                                               \
            const unsigned short* src =                                                \
                wb + (size_t)(d0 + row) * NN + (T) * 64 + 8 * (c ^ (row & 7));         \
            char* dst = reinterpret_cast<char*>(Bw) + (BUF) * 16384 + it * 4096 + w * 1024; \
            __builtin_amdgcn_global_load_lds((gconst_void*)src, (lds_void*)dst, 16, 0, 0);  \
        }                                                                              \
    }

#define P_COMPUTE(T, AFN)                                                              \
    {                                                                                  \
        unsigned long long bu0 = bra[T], bu1 = brb[T];                                 \
        _Pragma("unroll")                                                              \
        for (int kk = 0; kk < 2; ++kk) {                                               \
            const float4* ep = reinterpret_cast<const float4*>(e2g + (T) * 64 + kk * 32 + lh4 * 8); \
            float4 ea = ep[0], eb = ep[1];                                             \
            float ev[8] = {ea.x, ea.y, ea.z, ea.w, eb.x, eb.y, eb.z, eb.w};            \
            uint32_t bt0 = (uint32_t)(bu0 >> ((kk * 4 + lh4) * 8)) & 0xffu;            \
            uint32_t bt1 = (uint32_t)(bu1 >> ((kk * 4 + lh4) * 8)) & 0xffu;            \
            float p0[8], p1[8];                                                        \
            _Pragma("unroll")                                                          \
            for (int j = 0; j < 8; ++j) {                                              \
                float e = ev[j];                                                       \
                float s0 = r1a + e, q0 = fmaf(ALPHA_, e, r2a);                         \
                float s1 = r1b + e, q1 = fmaf(ALPHA_, e, r2b);                         \
                float x0 = __expf(fmaxf(s0, q0));                                      \
                float x1 = __expf(fmaxf(s1, q1));                                      \
                uint32_t m0 = (uint32_t)(((int32_t)(bt0 << (31 - j))) >> 31);          \
                uint32_t m1 = (uint32_t)(((int32_t)(bt1 << (31 - j))) >> 31);          \
                union { float f; uint32_t u; } u0, u1;                                 \
                u0.f = x0; u0.u &= m0; u1.f = x1; u1.u &= m1;                          \
                p0[j] = u0.f; p1[j] = u1.f;                                            \
            }                                                                          \
            union { short8 v; uint32_t u[4]; } k0, k1;                                 \
            _Pragma("unroll")                                                          \
            for (int i = 0; i < 4; ++i) {                                              \
                union { __hip_bfloat162 h; uint32_t u; } c0, c1;                       \
                c0.h = __float22bfloat162_rn(float2{p0[2 * i], p0[2 * i + 1]});        \
                c1.h = __float22bfloat162_rn(float2{p1[2 * i], p1[2 * i + 1]});        \
                k0.u[i] = c0.u; k1.u[i] = c1.u;                                        \
            }                                                                          \
            AFN[0][kk] = k0.v; AFN[1][kk] = k1.v;                                      \
        }                                                                              \
    }

#define MM(T, AF)                                                                      \
    {                                                                                  \
        const char* base = reinterpret_cast<const char*>(Bw) + ((T) & 1) * 16384;      \
        __builtin_amdgcn_s_setprio(1);                                                 \
        _Pragma("unroll")                                                              \
        for (int kk = 0; kk < 2; ++kk) {                                               \
            short8 bf[4];                                                              \
            _Pragma("unroll")                                                          \
            for (int cf = 0; cf < 4; ++cf) {                                           \
                int row = wd * 64 + cf * 16 + l15;                                     \
                int off = row * 128 + ((kk * 64 + lh4 * 16) ^ ((row & 7) << 4));       \
                bf[cf] = *reinterpret_cast<const short8*>(base + off);                 \
            }                                                                          \
            _Pragma("unroll")                                                          \
            for (int rf = 0; rf < 2; ++rf) {                                           \
                _Pragma("unroll")                                                      \
                for (int cf = 0; cf < 4; ++cf)                                         \
                    acc[rf][cf] = __builtin_amdgcn_mfma_f32_16x16x32_bf16(             \
                        AF[rf][kk], bf[cf], acc[rf][cf], 0, 0, 0);                     \
                accs[rf] = __builtin_amdgcn_mfma_f32_16x16x32_bf16(                    \
                    AF[rf][kk], ones, accs[rf], 0, 0, 0);                              \
            }                                                                          \
        }                                                                              \
        __builtin_amdgcn_s_setprio(0);                                                 \
    }

    // ---- prologue ----
    STAGE(0, 0)
    P_COMPUTE(0, afA)
    __syncthreads();

    // ---- main loop: 2 tiles per iteration (ping-pong A-fragments) ----
    for (int t = 0; t < NN / 64; t += 2) {
        // even tile t (buf 0): stage t+1 (always exists), compute P(t+1)
        STAGE(t + 1, 1)
        MM(t, afA)
        P_COMPUTE(t + 1, afB)
        __syncthreads();
        // odd tile t+1 (buf 1)
        if (t + 2 < NN / 64) {
            STAGE(t + 2, 0)
            MM(t + 1, afB)
            P_COMPUTE(t + 2, afA)
        } else {
            MM(t + 1, afB)
        }
        __syncthreads();
    }
#undef STAGE
#undef P_COMPUTE
#undef MM

    // ---- epilogue: normalize by MFMA row-sums, ELU, store ----
    #pragma unroll
    for (int rf = 0; rf < 2; ++rf) {
        float inv[4];
        #pragma unroll
        for (int j = 0; j < 4; ++j) inv[j] = 1.0f / accs[rf][j];
        #pragma unroll
        for (int cf = 0; cf < 4; ++cf) {
            int d = d0 + wd * 64 + cf * 16 + l15;
            #pragma unroll
            for (int j = 0; j < 4; ++j) {
                int nr = n0 + wn * 32 + rf * 16 + lh4 * 4 + j;
                float x = acc[rf][cf][j] * inv[j];
                x = x > 0.f ? x : (__expf(x) - 1.f);
                out[((size_t)b * NN + nr) * DOUT + d] = x;
            }
        }
    }
}

extern "C" void kernel_launch(void* const* d_in, const int* in_sizes, int n_in,
                              void* d_out, int out_size, void* d_ws, size_t ws_size,
                              hipStream_t stream) {
    (void)in_sizes; (void)n_in; (void)out_size; (void)ws_size;
    const float* h   = (const float*)d_in[0];
    const int*   adj = (const int*)d_in[1];
    const float* Ws  = (const float*)d_in[2];
    const float* a   = (const float*)d_in[3];
    float* out = (float*)d_out;

    char* ws = (char*)d_ws;
    unsigned short* hb  = (unsigned short*)(ws);              // 16,777,216 B
    unsigned short* wst = (unsigned short*)(ws + 16777216);   //  1,048,576 B
    unsigned short* wht = (unsigned short*)(ws + 17825792);   //  8,388,608 B
    float* e1  = (float*)(ws + 26214400);                     //     65,536 B
    float* e2  = (float*)(ws + 26279936);                     //     65,536 B
    uint32_t* bits = (uint32_t*)(ws + 26476544);              //  2,097,152 B

    k_prep<<<dim3(75776), dim3(256), 0, stream>>>(adj, (const float4*)h, Ws,
                                                  bits, (uint2*)hb, wst);
    k_gemm1<<<dim3(NN / 64, B_), dim3(256), 0, stream>>>(hb, wst, a, wht, e1, e2);
    k_attn<<<dim3(512), dim3(256), 0, stream>>>(wht, bits, e1, e2, out);
}

// Round 7
// 144.554 us; speedup vs baseline: 1.2046x; 1.2046x over previous
//
#include <hip/hip_runtime.h>
#include <hip/hip_bf16.h>
#include <stdint.h>

#define B_    4
#define NN    4096
#define DIN   512
#define DOUT  256
#define ALPHA_ 0.2f
#define LOG2E_ 1.44269504f

typedef __attribute__((ext_vector_type(8))) short short8;
typedef __attribute__((ext_vector_type(4))) float f32x4;

typedef const __attribute__((address_space(1))) void gconst_void;
typedef __attribute__((address_space(3))) void lds_void;

__device__ __forceinline__ unsigned short f2bf(float x) {
    union { float f; uint32_t u; } v; v.f = x;
    uint32_t r = v.u + 0x7FFFu + ((v.u >> 16) & 1u);
    return (unsigned short)(r >> 16);
}

// ---------------- K_prep: pack adj -> bits | h fp32->bf16 | Ws -> WsT bf16 ----------
__global__ __launch_bounds__(256) void k_prep(const int* __restrict__ adj,
                                              const float4* __restrict__ h4,
                                              const float* __restrict__ Ws,
                                              uint32_t* __restrict__ bits,
                                              uint2* __restrict__ hb,
                                              unsigned short* __restrict__ wst) {
    const int gid = blockIdx.x;
    const int tid = threadIdx.x;
    if (gid < 65536) {                       // pack adj: 67MB -> 2MB
        int idx = gid * 256 + tid;
        unsigned long long m = __ballot(adj[idx] > 0);
        if ((tid & 63) == 0)
            *reinterpret_cast<unsigned long long*>(bits + ((idx >> 6) << 1)) = m;
    } else if (gid < 73728) {                // h -> bf16 (float4 granularity)
        int idx = (gid - 65536) * 256 + tid;
        float4 v = h4[idx];
        uint2 o;
        o.x = (uint32_t)f2bf(v.x) | ((uint32_t)f2bf(v.y) << 16);
        o.y = (uint32_t)f2bf(v.z) | ((uint32_t)f2bf(v.w) << 16);
        hb[idx] = o;
    } else {                                 // Ws (B,DIN,DOUT) -> WsT (B,DOUT,DIN)
        int idx = (gid - 73728) * 256 + tid;
        int k = idx & (DIN - 1);
        int o = (idx >> 9) & (DOUT - 1);
        int b = idx >> 17;
        wst[idx] = f2bf(Ws[((size_t)b * DIN + k) * DOUT + o]);
    }
}

// ---------------- K1: WhT[b][d][m] = (h @ Ws)^T + fused e1/e2 epilogue --------------
// e1/e2 are stored PRE-SCALED by log2(e) so k_attn can use exp2 directly.
__global__ __launch_bounds__(256) void k_gemm1(const unsigned short* __restrict__ hb,
                                               const unsigned short* __restrict__ wst,
                                               const float* __restrict__ a,
                                               unsigned short* __restrict__ wht,
                                               float* __restrict__ e1,
                                               float* __restrict__ e2) {
    __shared__ unsigned short Ah[64 * 64];    // [n][k] swizzled rows (128B)
    __shared__ unsigned short Bw[256 * 64];   // [d][k] swizzled rows (128B)
    __shared__ float e1s[64], e2s[64];
    const int tid = threadIdx.x;
    const int w = tid >> 6, lane = tid & 63;
    const int l15 = lane & 15, lhi = lane >> 4;
    const int b = blockIdx.y;
    const int n0 = blockIdx.x * 64;
    const unsigned short* hrow = hb + ((size_t)b * NN + n0) * DIN;
    const unsigned short* wrow = wst + (size_t)b * DOUT * DIN;

    if (tid < 64) { e1s[tid] = 0.f; e2s[tid] = 0.f; }

    f32x4 acc[4][4] = {};

    for (int kt = 0; kt < DIN / 64; ++kt) {
        const int k0 = kt * 64;
        #pragma unroll
        for (int it = 0; it < 2; ++it) {     // stage A: 8KB
            int q = it * 256 + tid;
            int row = q >> 3, c = q & 7;
            const unsigned short* src = hrow + (size_t)row * DIN + k0 + 8 * (c ^ (row & 7));
            char* dst = reinterpret_cast<char*>(Ah) + it * 4096 + w * 1024;
            __builtin_amdgcn_global_load_lds((gconst_void*)src, (lds_void*)dst, 16, 0, 0);
        }
        #pragma unroll
        for (int it = 0; it < 8; ++it) {     // stage B: 32KB
            int q = it * 256 + tid;
            int row = q >> 3, c = q & 7;
            const unsigned short* src = wrow + (size_t)row * DIN + k0 + 8 * (c ^ (row & 7));
            char* dst = reinterpret_cast<char*>(Bw) + it * 4096 + w * 1024;
            __builtin_amdgcn_global_load_lds((gconst_void*)src, (lds_void*)dst, 16, 0, 0);
        }
        __syncthreads();
        #pragma unroll
        for (int kk = 0; kk < 2; ++kk) {
            short8 af[4], bfr[4];
            #pragma unroll
            for (int rf = 0; rf < 4; ++rf) {
                int row = rf * 16 + l15;
                int off = row * 128 + ((kk * 64 + lhi * 16) ^ ((row & 7) << 4));
                af[rf] = *reinterpret_cast<const short8*>(reinterpret_cast<const char*>(Ah) + off);
            }
            #pragma unroll
            for (int cf = 0; cf < 4; ++cf) {
                int row = w * 64 + cf * 16 + l15;
                int off = row * 128 + ((kk * 64 + lhi * 16) ^ ((row & 7) << 4));
                bfr[cf] = *reinterpret_cast<const short8*>(reinterpret_cast<const char*>(Bw) + off);
            }
            #pragma unroll
            for (int rf = 0; rf < 4; ++rf)
                #pragma unroll
                for (int cf = 0; cf < 4; ++cf)
                    acc[rf][cf] = __builtin_amdgcn_mfma_f32_16x16x32_bf16(af[rf], bfr[cf], acc[rf][cf], 0, 0, 0);
        }
        __syncthreads();
    }
    // WhT write (bf16, transposed)
    unsigned short* wb = wht + (size_t)b * DOUT * NN;
    #pragma unroll
    for (int rf = 0; rf < 4; ++rf) {
        #pragma unroll
        for (int cf = 0; cf < 4; ++cf) {
            int d = w * 64 + cf * 16 + l15;
            int m = n0 + rf * 16 + lhi * 4;
            uint2 pk;
            pk.x = (uint32_t)f2bf(acc[rf][cf][0]) | ((uint32_t)f2bf(acc[rf][cf][1]) << 16);
            pk.y = (uint32_t)f2bf(acc[rf][cf][2]) | ((uint32_t)f2bf(acc[rf][cf][3]) << 16);
            *reinterpret_cast<uint2*>(wb + (size_t)d * NN + m) = pk;
        }
    }
    // fused e1/e2 via shfl-reduce over the 16-lane fragment columns
    const float* ab = a + b * 2 * DOUT;
    float a1v[4], a2v[4];
    #pragma unroll
    for (int cf = 0; cf < 4; ++cf) {
        int d = w * 64 + cf * 16 + l15;
        a1v[cf] = ab[d];
        a2v[cf] = ab[DOUT + d];
    }
    #pragma unroll
    for (int rf = 0; rf < 4; ++rf) {
        #pragma unroll
        for (int j = 0; j < 4; ++j) {
            float p1 = 0.f, p2 = 0.f;
            #pragma unroll
            for (int cf = 0; cf < 4; ++cf) {
                p1 = fmaf(acc[rf][cf][j], a1v[cf], p1);
                p2 = fmaf(acc[rf][cf][j], a2v[cf], p2);
            }
            #pragma unroll
            for (int msk = 1; msk < 16; msk <<= 1) {
                p1 += __shfl_xor(p1, msk);
                p2 += __shfl_xor(p2, msk);
            }
            if (l15 == 0) {
                atomicAdd(&e1s[rf * 16 + lhi * 4 + j], p1);
                atomicAdd(&e2s[rf * 16 + lhi * 4 + j], p2);
            }
        }
    }
    __syncthreads();
    if (tid < 64) {
        e1[b * NN + n0 + tid] = e1s[tid] * LOG2E_;   // log2-domain for exp2
        e2[b * NN + n0 + tid] = e2s[tid] * LOG2E_;
    }
}

// ---------------- K4: h' = softmax(P)@Wh ------------------------------------------
// block 64n x 256d, 512 threads = 8 waves (2n x 4d), each 32n x 64d (acc 2x4).
// P computed ONCE per block (no dup) into LDS Pt; exp2 in log2 domain;
// denominators via ones-column MFMA. LDS = 64KB Bw dbuf + 16KB Pt dbuf = 80KB
// -> 2 blocks/CU = 16 waves/CU = 4 waves/SIMD.
__global__ __launch_bounds__(512, 4) void k_attn(const unsigned short* __restrict__ wht,
                                                 const uint32_t* __restrict__ bits,
                                                 const float* __restrict__ e1,
                                                 const float* __restrict__ e2,
                                                 float* __restrict__ out) {
    __shared__ unsigned short Bw[2 * 256 * 64];  // WhT tile dbuf, swizzled rows (64KB)
    __shared__ unsigned short Pt[2 * 64 * 64];   // P tile dbuf, swizzled rows (16KB)

    const int tid = threadIdx.x;
    const int w = tid >> 6, lane = tid & 63;
    const int l15 = lane & 15, lh4 = lane >> 4;
    const int wn = w >> 2, wd = w & 3;

    // XCD-aware bijective swizzle: 256 blocks, 32/XCD; 2 XCDs share one batch
    const int bid = blockIdx.x;
    const int wg = ((bid & 7) << 5) | (bid >> 3);
    const int b  = wg >> 6;
    const int n0 = (wg & 63) << 6;

    // P mapping: pr = row (0..63), pc = 8-m group (0..7)
    const int pr = tid >> 3, pc = tid & 7;
    const float r1p = e1[b * NN + n0 + pr];     // log2-scaled
    const float r2p = ALPHA_ * r1p;
    const uint8_t* browb = reinterpret_cast<const uint8_t*>(bits) + (size_t)(n0 + pr) * (NN / 8);
    const float* e2g = e2 + b * NN;
    const unsigned short* wb = wht + (size_t)b * DOUT * NN;

    f32x4 acc[2][4] = {};
    f32x4 accs[2] = {};
    short8 ones;
    {
        union { short8 v; uint32_t u[4]; } ov;
        ov.u[0] = 0x3F803F80u; ov.u[1] = 0x3F803F80u;
        ov.u[2] = 0x3F803F80u; ov.u[3] = 0x3F803F80u;
        ones = ov.v;
    }

#define STAGE(T, BUF)                                                                  \
    {                                                                                  \
        _Pragma("unroll")                                                              \
        for (int it = 0; it < 4; ++it) {                                               \
            int q = it * 512 + tid;                                                    \
            int row = q >> 3, c = q & 7;                                               \
            const unsigned short* src =                                                \
                wb + (size_t)row * NN + (T) * 64 + 8 * (c ^ (row & 7));                \
            char* dst = reinterpret_cast<char*>(Bw) + (BUF) * 32768 + it * 8192 + w * 1024; \
            __builtin_amdgcn_global_load_lds((gconst_void*)src, (lds_void*)dst, 16, 0, 0);  \
        }                                                                              \
    }

#define P_BODY(EA, EB, BB, DSTBASE)                                                    \
    {                                                                                  \
        float pv[8] = {EA.x, EA.y, EA.z, EA.w, EB.x, EB.y, EB.z, EB.w};                \
        _Pragma("unroll")                                                              \
        for (int j = 0; j < 8; ++j) {                                                  \
            float e = pv[j];                                                           \
            float s = r1p + e;                                                         \
            float tt = fmaf(ALPHA_, e, r2p);                                           \
            float x = exp2f(fmaxf(s, tt));                                             \
            uint32_t msk = (uint32_t)(((int32_t)((BB) << (31 - j))) >> 31);            \
            union { float f; uint32_t u; } pu; pu.f = x; pu.u &= msk;                  \
            pv[j] = pu.f;                                                              \
        }                                                                              \
        union { short8 v; uint32_t u[4]; } k0;                                         \
        _Pragma("unroll")                                                              \
        for (int i = 0; i < 4; ++i) {                                                  \
            union { __hip_bfloat162 h; uint32_t u; } c0;                               \
            c0.h = __float22bfloat162_rn(float2{pv[2 * i], pv[2 * i + 1]});            \
            k0.u[i] = c0.u;                                                            \
        }                                                                              \
        *reinterpret_cast<short8*>((DSTBASE) + pr * 128 +                              \
                                   ((pc * 16) ^ ((pr & 7) << 4))) = k0.v;              \
    }

#define MM(CUR)                                                                        \
    {                                                                                  \
        const char* bwb = reinterpret_cast<const char*>(Bw) + (CUR) * 32768;           \
        const char* ptb = reinterpret_cast<const char*>(Pt) + (CUR) * 8192;            \
        __builtin_amdgcn_s_setprio(1);                                                 \
        _Pragma("unroll")                                                              \
        for (int kk = 0; kk < 2; ++kk) {                                               \
            short8 af[2], bf[4];                                                       \
            _Pragma("unroll")                                                          \
            for (int rf = 0; rf < 2; ++rf) {                                           \
                int row = wn * 32 + rf * 16 + l15;                                     \
                int off = row * 128 + ((kk * 64 + lh4 * 16) ^ ((row & 7) << 4));       \
                af[rf] = *reinterpret_cast<const short8*>(ptb + off);                  \
            }                                                                          \
            _Pragma("unroll")                                                          \
            for (int cf = 0; cf < 4; ++cf) {                                           \
                int row = wd * 64 + cf * 16 + l15;                                     \
                int off = row * 128 + ((kk * 64 + lh4 * 16) ^ ((row & 7) << 4));       \
                bf[cf] = *reinterpret_cast<const short8*>(bwb + off);                  \
            }                                                                          \
            _Pragma("unroll")                                                          \
            for (int rf = 0; rf < 2; ++rf) {                                           \
                _Pragma("unroll")                                                      \
                for (int cf = 0; cf < 4; ++cf)                                         \
                    acc[rf][cf] = __builtin_amdgcn_mfma_f32_16x16x32_bf16(             \
                        af[rf], bf[cf], acc[rf][cf], 0, 0, 0);                         \
                accs[rf] = __builtin_amdgcn_mfma_f32_16x16x32_bf16(                    \
                    af[rf], ones, accs[rf], 0, 0, 0);                                  \
            }                                                                          \
        }                                                                              \
        __builtin_amdgcn_s_setprio(0);                                                 \
    }

    // ---- prologue: stage + P for tile 0 ----
    STAGE(0, 0)
    {
        uint32_t bb = browb[pc];
        const float4* ep = reinterpret_cast<const float4*>(e2g + pc * 8);
        float4 ea = ep[0], eb = ep[1];
        P_BODY(ea, eb, bb, reinterpret_cast<char*>(Pt))
    }
    __syncthreads();

    // ---- main loop: 1 barrier/tile; stage(t+1)+P(t+1) overlap MFMA(t) ----
    for (int t = 0; t < NN / 64; ++t) {
        const int cur = t & 1;
        uint32_t bbN = 0;
        float4 ea, eb;
        if (t < NN / 64 - 1) {
            STAGE(t + 1, cur ^ 1)
            bbN = browb[(t + 1) * 8 + pc];
            const float4* ep = reinterpret_cast<const float4*>(e2g + (t + 1) * 64 + pc * 8);
            ea = ep[0]; eb = ep[1];
        }
        MM(cur)
        if (t < NN / 64 - 1) {
            P_BODY(ea, eb, bbN, reinterpret_cast<char*>(Pt) + (cur ^ 1) * 8192)
            __syncthreads();
        }
    }
#undef STAGE
#undef P_BODY
#undef MM

    // ---- epilogue: normalize by MFMA row-sums, ELU, store ----
    #pragma unroll
    for (int rf = 0; rf < 2; ++rf) {
        float inv[4];
        #pragma unroll
        for (int j = 0; j < 4; ++j) inv[j] = 1.0f / accs[rf][j];
        #pragma unroll
        for (int cf = 0; cf < 4; ++cf) {
            int d = wd * 64 + cf * 16 + l15;
            #pragma unroll
            for (int j = 0; j < 4; ++j) {
                int nr = n0 + wn * 32 + rf * 16 + lh4 * 4 + j;
                float x = acc[rf][cf][j] * inv[j];
                x = x > 0.f ? x : (__expf(x) - 1.f);
                out[((size_t)b * NN + nr) * DOUT + d] = x;
            }
        }
    }
}

extern "C" void kernel_launch(void* const* d_in, const int* in_sizes, int n_in,
                              void* d_out, int out_size, void* d_ws, size_t ws_size,
                              hipStream_t stream) {
    (void)in_sizes; (void)n_in; (void)out_size; (void)ws_size;
    const float* h   = (const float*)d_in[0];
    const int*   adj = (const int*)d_in[1];
    const float* Ws  = (const float*)d_in[2];
    const float* a   = (const float*)d_in[3];
    float* out = (float*)d_out;

    char* ws = (char*)d_ws;
    unsigned short* hb  = (unsigned short*)(ws);              // 16,777,216 B
    unsigned short* wst = (unsigned short*)(ws + 16777216);   //  1,048,576 B
    unsigned short* wht = (unsigned short*)(ws + 17825792);   //  8,388,608 B
    float* e1  = (float*)(ws + 26214400);                     //     65,536 B
    float* e2  = (float*)(ws + 26279936);                     //     65,536 B
    uint32_t* bits = (uint32_t*)(ws + 26476544);              //  2,097,152 B

    k_prep<<<dim3(75776), dim3(256), 0, stream>>>(adj, (const float4*)h, Ws,
                                                  bits, (uint2*)hb, wst);
    k_gemm1<<<dim3(NN / 64, B_), dim3(256), 0, stream>>>(hb, wst, a, wht, e1, e2);
    k_attn<<<dim3(256), dim3(512), 0, stream>>>(wht, bits, e1, e2, out);
}

// Round 8
// 143.920 us; speedup vs baseline: 1.2099x; 1.0044x over previous
//
#include <hip/hip_runtime.h>
#include <hip/hip_bf16.h>
#include <stdint.h>

#define B_    4
#define NN    4096
#define DIN   512
#define DOUT  256
#define ALPHA_ 0.2f
#define LOG2E_ 1.44269504f

typedef __attribute__((ext_vector_type(8))) short short8;
typedef __attribute__((ext_vector_type(4))) float f32x4;

typedef const __attribute__((address_space(1))) void gconst_void;
typedef __attribute__((address_space(3))) void lds_void;

__device__ __forceinline__ unsigned short f2bf(float x) {
    union { float f; uint32_t u; } v; v.f = x;
    uint32_t r = v.u + 0x7FFFu + ((v.u >> 16) & 1u);
    return (unsigned short)(r >> 16);
}

// ---------------- K_prep: pack adj -> bits | h fp32->bf16 | Ws -> WsT bf16 ----------
__global__ __launch_bounds__(256) void k_prep(const int* __restrict__ adj,
                                              const float4* __restrict__ h4,
                                              const float* __restrict__ Ws,
                                              uint32_t* __restrict__ bits,
                                              uint2* __restrict__ hb,
                                              unsigned short* __restrict__ wst) {
    const int gid = blockIdx.x;
    const int tid = threadIdx.x;
    if (gid < 65536) {                       // pack adj: 67MB -> 2MB
        int idx = gid * 256 + tid;
        unsigned long long m = __ballot(adj[idx] > 0);
        if ((tid & 63) == 0)
            *reinterpret_cast<unsigned long long*>(bits + ((idx >> 6) << 1)) = m;
    } else if (gid < 73728) {                // h -> bf16 (float4 granularity)
        int idx = (gid - 65536) * 256 + tid;
        float4 v = h4[idx];
        uint2 o;
        o.x = (uint32_t)f2bf(v.x) | ((uint32_t)f2bf(v.y) << 16);
        o.y = (uint32_t)f2bf(v.z) | ((uint32_t)f2bf(v.w) << 16);
        hb[idx] = o;
    } else {                                 // Ws (B,DIN,DOUT) -> WsT (B,DOUT,DIN)
        int idx = (gid - 73728) * 256 + tid;
        int k = idx & (DIN - 1);
        int o = (idx >> 9) & (DOUT - 1);
        int b = idx >> 17;
        wst[idx] = f2bf(Ws[((size_t)b * DIN + k) * DOUT + o]);
    }
}

// ---------------- K1: WhT[b][d][m] = (h @ Ws)^T + fused e1/e2 epilogue --------------
// e1/e2 are stored PRE-SCALED by log2(e) so k_attn can use exp2 directly.
__global__ __launch_bounds__(256) void k_gemm1(const unsigned short* __restrict__ hb,
                                               const unsigned short* __restrict__ wst,
                                               const float* __restrict__ a,
                                               unsigned short* __restrict__ wht,
                                               float* __restrict__ e1,
                                               float* __restrict__ e2) {
    __shared__ unsigned short Ah[64 * 64];    // [n][k] swizzled rows (128B)
    __shared__ unsigned short Bw[256 * 64];   // [d][k] swizzled rows (128B)
    __shared__ float e1s[64], e2s[64];
    const int tid = threadIdx.x;
    const int w = tid >> 6, lane = tid & 63;
    const int l15 = lane & 15, lhi = lane >> 4;
    const int b = blockIdx.y;
    const int n0 = blockIdx.x * 64;
    const unsigned short* hrow = hb + ((size_t)b * NN + n0) * DIN;
    const unsigned short* wrow = wst + (size_t)b * DOUT * DIN;

    if (tid < 64) { e1s[tid] = 0.f; e2s[tid] = 0.f; }

    f32x4 acc[4][4] = {};

    for (int kt = 0; kt < DIN / 64; ++kt) {
        const int k0 = kt * 64;
        #pragma unroll
        for (int it = 0; it < 2; ++it) {     // stage A: 8KB
            int q = it * 256 + tid;
            int row = q >> 3, c = q & 7;
            const unsigned short* src = hrow + (size_t)row * DIN + k0 + 8 * (c ^ (row & 7));
            char* dst = reinterpret_cast<char*>(Ah) + it * 4096 + w * 1024;
            __builtin_amdgcn_global_load_lds((gconst_void*)src, (lds_void*)dst, 16, 0, 0);
        }
        #pragma unroll
        for (int it = 0; it < 8; ++it) {     // stage B: 32KB
            int q = it * 256 + tid;
            int row = q >> 3, c = q & 7;
            const unsigned short* src = wrow + (size_t)row * DIN + k0 + 8 * (c ^ (row & 7));
            char* dst = reinterpret_cast<char*>(Bw) + it * 4096 + w * 1024;
            __builtin_amdgcn_global_load_lds((gconst_void*)src, (lds_void*)dst, 16, 0, 0);
        }
        __syncthreads();
        #pragma unroll
        for (int kk = 0; kk < 2; ++kk) {
            short8 af[4], bfr[4];
            #pragma unroll
            for (int rf = 0; rf < 4; ++rf) {
                int row = rf * 16 + l15;
                int off = row * 128 + ((kk * 64 + lhi * 16) ^ ((row & 7) << 4));
                af[rf] = *reinterpret_cast<const short8*>(reinterpret_cast<const char*>(Ah) + off);
            }
            #pragma unroll
            for (int cf = 0; cf < 4; ++cf) {
                int row = w * 64 + cf * 16 + l15;
                int off = row * 128 + ((kk * 64 + lhi * 16) ^ ((row & 7) << 4));
                bfr[cf] = *reinterpret_cast<const short8*>(reinterpret_cast<const char*>(Bw) + off);
            }
            #pragma unroll
            for (int rf = 0; rf < 4; ++rf)
                #pragma unroll
                for (int cf = 0; cf < 4; ++cf)
                    acc[rf][cf] = __builtin_amdgcn_mfma_f32_16x16x32_bf16(af[rf], bfr[cf], acc[rf][cf], 0, 0, 0);
        }
        __syncthreads();
    }
    // WhT write (bf16, transposed)
    unsigned short* wb = wht + (size_t)b * DOUT * NN;
    #pragma unroll
    for (int rf = 0; rf < 4; ++rf) {
        #pragma unroll
        for (int cf = 0; cf < 4; ++cf) {
            int d = w * 64 + cf * 16 + l15;
            int m = n0 + rf * 16 + lhi * 4;
            uint2 pk;
            pk.x = (uint32_t)f2bf(acc[rf][cf][0]) | ((uint32_t)f2bf(acc[rf][cf][1]) << 16);
            pk.y = (uint32_t)f2bf(acc[rf][cf][2]) | ((uint32_t)f2bf(acc[rf][cf][3]) << 16);
            *reinterpret_cast<uint2*>(wb + (size_t)d * NN + m) = pk;
        }
    }
    // fused e1/e2 via shfl-reduce over the 16-lane fragment columns
    const float* ab = a + b * 2 * DOUT;
    float a1v[4], a2v[4];
    #pragma unroll
    for (int cf = 0; cf < 4; ++cf) {
        int d = w * 64 + cf * 16 + l15;
        a1v[cf] = ab[d];
        a2v[cf] = ab[DOUT + d];
    }
    #pragma unroll
    for (int rf = 0; rf < 4; ++rf) {
        #pragma unroll
        for (int j = 0; j < 4; ++j) {
            float p1 = 0.f, p2 = 0.f;
            #pragma unroll
            for (int cf = 0; cf < 4; ++cf) {
                p1 = fmaf(acc[rf][cf][j], a1v[cf], p1);
                p2 = fmaf(acc[rf][cf][j], a2v[cf], p2);
            }
            #pragma unroll
            for (int msk = 1; msk < 16; msk <<= 1) {
                p1 += __shfl_xor(p1, msk);
                p2 += __shfl_xor(p2, msk);
            }
            if (l15 == 0) {
                atomicAdd(&e1s[rf * 16 + lhi * 4 + j], p1);
                atomicAdd(&e2s[rf * 16 + lhi * 4 + j], p2);
            }
        }
    }
    __syncthreads();
    if (tid < 64) {
        e1[b * NN + n0 + tid] = e1s[tid] * LOG2E_;   // log2-domain for exp2
        e2[b * NN + n0 + tid] = e2s[tid] * LOG2E_;
    }
}

// ---------------- K4: h' numerators, K-split x2, atomic combine --------------------
// block 64n x 256d x half-K, 512 threads = 8 waves (2n x 4d), each 32n x 64d.
// grid 512 -> 2 blocks/CU (LDS 72KB) = 16 waves/CU. Unnormalized acc + ones-MFMA
// row-sums; partials combined via fp32 atomicAdd into zeroed out/sums.
__global__ __launch_bounds__(512, 4) void k_attn(const unsigned short* __restrict__ wht,
                                                 const uint32_t* __restrict__ bits,
                                                 const float* __restrict__ e1,
                                                 const float* __restrict__ e2,
                                                 float* __restrict__ out,
                                                 float* __restrict__ sums) {
    __shared__ unsigned short Bw[2 * 256 * 64];  // WhT tile dbuf, swizzled rows (64KB)
    __shared__ unsigned short Pt[64 * 64];       // P tile, single buffer (8KB)

    const int tid = threadIdx.x;
    const int w = tid >> 6, lane = tid & 63;
    const int l15 = lane & 15, lh4 = lane >> 4;
    const int wn = w >> 2, wd = w & 3;

    // XCD swizzle: 512 blocks; xcd g = (b,ch-half); within: 32 n-chunks x 2 k-halves
    const int bid = blockIdx.x;
    const int wg = ((bid & 7) << 6) | (bid >> 3);
    const int g  = wg >> 6;            // == bid & 7 (XCD id)
    const int b  = g >> 1;
    const int n0 = ((g & 1) * 32 + (wg & 31)) << 6;
    const int T0 = ((wg >> 5) & 1) * 32;          // k-half: tiles [T0, T0+32)

    // P mapping: pr = row (0..63), pc = 8-m group (0..7)
    const int pr = tid >> 3, pc = tid & 7;
    const float r1p = e1[b * NN + n0 + pr];       // log2-scaled
    const float r2p = ALPHA_ * r1p;
    const uint8_t* browb = reinterpret_cast<const uint8_t*>(bits) + (size_t)(n0 + pr) * (NN / 8);
    const float* e2g = e2 + b * NN;
    const unsigned short* wb = wht + (size_t)b * DOUT * NN;

    f32x4 acc[2][4] = {};
    f32x4 accs[2] = {};
    short8 ones;
    {
        union { short8 v; uint32_t u[4]; } ov;
        ov.u[0] = 0x3F803F80u; ov.u[1] = 0x3F803F80u;
        ov.u[2] = 0x3F803F80u; ov.u[3] = 0x3F803F80u;
        ones = ov.v;
    }

#define STAGE(T, BUF)                                                                  \
    {                                                                                  \
        _Pragma("unroll")                                                              \
        for (int it = 0; it < 4; ++it) {                                               \
            int q = it * 512 + tid;                                                    \
            int row = q >> 3, c = q & 7;                                               \
            const unsigned short* src =                                                \
                wb + (size_t)row * NN + (T) * 64 + 8 * (c ^ (row & 7));                \
            char* dst = reinterpret_cast<char*>(Bw) + (BUF) * 32768 + it * 8192 + w * 1024; \
            __builtin_amdgcn_global_load_lds((gconst_void*)src, (lds_void*)dst, 16, 0, 0);  \
        }                                                                              \
    }

#define P_BODY(EA, EB, BB)                                                             \
    {                                                                                  \
        float pv[8] = {EA.x, EA.y, EA.z, EA.w, EB.x, EB.y, EB.z, EB.w};                \
        _Pragma("unroll")                                                              \
        for (int j = 0; j < 8; ++j) {                                                  \
            float e = pv[j];                                                           \
            float s = r1p + e;                                                         \
            float tt = fmaf(ALPHA_, e, r2p);                                           \
            float x = exp2f(fmaxf(s, tt));                                             \
            uint32_t msk = (uint32_t)(((int32_t)((BB) << (31 - j))) >> 31);            \
            union { float f; uint32_t u; } pu; pu.f = x; pu.u &= msk;                  \
            pv[j] = pu.f;                                                              \
        }                                                                              \
        union { short8 v; uint32_t u[4]; } k0;                                         \
        _Pragma("unroll")                                                              \
        for (int i = 0; i < 4; ++i) {                                                  \
            union { __hip_bfloat162 h; uint32_t u; } c0;                               \
            c0.h = __float22bfloat162_rn(float2{pv[2 * i], pv[2 * i + 1]});            \
            k0.u[i] = c0.u;                                                            \
        }                                                                              \
        *reinterpret_cast<short8*>(reinterpret_cast<char*>(Pt) + pr * 128 +            \
                                   ((pc * 16) ^ ((pr & 7) << 4))) = k0.v;              \
    }

#define MM(CUR)                                                                        \
    {                                                                                  \
        const char* bwb = reinterpret_cast<const char*>(Bw) + (CUR) * 32768;           \
        const char* ptb = reinterpret_cast<const char*>(Pt);                           \
        __builtin_amdgcn_s_setprio(1);                                                 \
        _Pragma("unroll")                                                              \
        for (int kk = 0; kk < 2; ++kk) {                                               \
            short8 af[2], bf[4];                                                       \
            _Pragma("unroll")                                                          \
            for (int rf = 0; rf < 2; ++rf) {                                           \
                int row = wn * 32 + rf * 16 + l15;                                     \
                int off = row * 128 + ((kk * 64 + lh4 * 16) ^ ((row & 7) << 4));       \
                af[rf] = *reinterpret_cast<const short8*>(ptb + off);                  \
            }                                                                          \
            _Pragma("unroll")                                                          \
            for (int cf = 0; cf < 4; ++cf) {                                           \
                int row = wd * 64 + cf * 16 + l15;                                     \
                int off = row * 128 + ((kk * 64 + lh4 * 16) ^ ((row & 7) << 4));       \
                bf[cf] = *reinterpret_cast<const short8*>(bwb + off);                  \
            }                                                                          \
            _Pragma("unroll")                                                          \
            for (int rf = 0; rf < 2; ++rf) {                                           \
                _Pragma("unroll")                                                      \
                for (int cf = 0; cf < 4; ++cf)                                         \
                    acc[rf][cf] = __builtin_amdgcn_mfma_f32_16x16x32_bf16(             \
                        af[rf], bf[cf], acc[rf][cf], 0, 0, 0);                         \
                accs[rf] = __builtin_amdgcn_mfma_f32_16x16x32_bf16(                    \
                    af[rf], ones, accs[rf], 0, 0, 0);                                  \
            }                                                                          \
        }                                                                              \
        __builtin_amdgcn_s_setprio(0);                                                 \
    }

    // ---- prologue: stage + P for first tile of this k-half ----
    STAGE(T0, 0)
    {
        uint32_t bb = browb[T0 * 8 + pc];
        const float4* ep = reinterpret_cast<const float4*>(e2g + T0 * 64 + pc * 8);
        float4 ea = ep[0], eb = ep[1];
        P_BODY(ea, eb, bb)
    }
    __syncthreads();

    // ---- main loop over 32 tiles: stage(t+1) overlaps MFMA(t); Pt single-buffered --
    for (int t = 0; t < 32; ++t) {
        const int cur = t & 1;
        uint32_t bbN = 0;
        float4 ea, eb;
        if (t < 31) {
            STAGE(T0 + t + 1, cur ^ 1)
            bbN = browb[(T0 + t + 1) * 8 + pc];
            const float4* ep = reinterpret_cast<const float4*>(e2g + (T0 + t + 1) * 64 + pc * 8);
            ea = ep[0]; eb = ep[1];
        }
        MM(cur)
        __syncthreads();                 // Pt reads done + own stage drained
        if (t < 31) {
            P_BODY(ea, eb, bbN)
            __syncthreads();             // Pt(t+1) visible to all waves
        }
    }
#undef STAGE
#undef P_BODY
#undef MM

    // ---- epilogue: atomic-combine partial numerators and row sums ----
    #pragma unroll
    for (int rf = 0; rf < 2; ++rf) {
        #pragma unroll
        for (int cf = 0; cf < 4; ++cf) {
            int d = wd * 64 + cf * 16 + l15;
            #pragma unroll
            for (int j = 0; j < 4; ++j) {
                int nr = n0 + wn * 32 + rf * 16 + lh4 * 4 + j;
                atomicAdd(&out[((size_t)b * NN + nr) * DOUT + d], acc[rf][cf][j]);
            }
        }
    }
    if (wd == 0 && l15 == 0) {
        #pragma unroll
        for (int rf = 0; rf < 2; ++rf)
            #pragma unroll
            for (int j = 0; j < 4; ++j) {
                int nr = n0 + wn * 32 + rf * 16 + lh4 * 4 + j;
                atomicAdd(&sums[b * NN + nr], accs[rf][j]);
            }
    }
}

// ---------------- K5: finalize — out = ELU(out / sums[row]) in place ----------------
__global__ __launch_bounds__(256) void k_final(const float* __restrict__ sums,
                                               float* __restrict__ out) {
    int f4 = blockIdx.x * 256 + threadIdx.x;     // float4 index
    int row = f4 >> 6;                           // 64 float4 per (b,n) row
    float inv = 1.0f / sums[row];
    float4 v = reinterpret_cast<const float4*>(out)[f4];
    v.x *= inv; v.y *= inv; v.z *= inv; v.w *= inv;
    v.x = v.x > 0.f ? v.x : (__expf(v.x) - 1.f);
    v.y = v.y > 0.f ? v.y : (__expf(v.y) - 1.f);
    v.z = v.z > 0.f ? v.z : (__expf(v.z) - 1.f);
    v.w = v.w > 0.f ? v.w : (__expf(v.w) - 1.f);
    reinterpret_cast<float4*>(out)[f4] = v;
}

extern "C" void kernel_launch(void* const* d_in, const int* in_sizes, int n_in,
                              void* d_out, int out_size, void* d_ws, size_t ws_size,
                              hipStream_t stream) {
    (void)in_sizes; (void)n_in; (void)out_size; (void)ws_size;
    const float* h   = (const float*)d_in[0];
    const int*   adj = (const int*)d_in[1];
    const float* Ws  = (const float*)d_in[2];
    const float* a   = (const float*)d_in[3];
    float* out = (float*)d_out;

    char* ws = (char*)d_ws;
    unsigned short* hb  = (unsigned short*)(ws);              // 16,777,216 B
    unsigned short* wst = (unsigned short*)(ws + 16777216);   //  1,048,576 B
    unsigned short* wht = (unsigned short*)(ws + 17825792);   //  8,388,608 B
    float* e1  = (float*)(ws + 26214400);                     //     65,536 B
    float* e2  = (float*)(ws + 26279936);                     //     65,536 B
    float* sums = (float*)(ws + 26411008);                    //     65,536 B
    uint32_t* bits = (uint32_t*)(ws + 26476544);              //  2,097,152 B

    hipMemsetAsync(out, 0, (size_t)B_ * NN * DOUT * sizeof(float), stream);
    hipMemsetAsync(sums, 0, (size_t)B_ * NN * sizeof(float), stream);
    k_prep<<<dim3(75776), dim3(256), 0, stream>>>(adj, (const float4*)h, Ws,
                                                  bits, (uint2*)hb, wst);
    k_gemm1<<<dim3(NN / 64, B_), dim3(256), 0, stream>>>(hb, wst, a, wht, e1, e2);
    k_attn<<<dim3(512), dim3(512), 0, stream>>>(wht, bits, e1, e2, out, sums);
    k_final<<<dim3(B_ * NN * DOUT / 1024), dim3(256), 0, stream>>>(sums, out);
}

// Round 9
// 132.278 us; speedup vs baseline: 1.3164x; 1.0880x over previous
//
#include <hip/hip_runtime.h>
#include <hip/hip_bf16.h>
#include <stdint.h>

#define B_    4
#define NN    4096
#define DIN   512
#define DOUT  256
#define ALPHA_ 0.2f

typedef __attribute__((ext_vector_type(8))) short short8;
typedef __attribute__((ext_vector_type(4))) float f32x4;
typedef __attribute__((ext_vector_type(2))) float f32x2;

typedef const __attribute__((address_space(1))) void gconst_void;
typedef __attribute__((address_space(3))) void lds_void;

__device__ __forceinline__ unsigned short f2bf(float x) {
    union { float f; uint32_t u; } v; v.f = x;
    uint32_t r = v.u + 0x7FFFu + ((v.u >> 16) & 1u);
    return (unsigned short)(r >> 16);
}

// ---------------- K_prep: grid-stride (2048 blocks): pack adj | h->bf16 | WsT -------
__global__ __launch_bounds__(256) void k_prep(const int* __restrict__ adj,
                                              const float4* __restrict__ h4,
                                              const float* __restrict__ Ws,
                                              uint32_t* __restrict__ bits,
                                              uint2* __restrict__ hb,
                                              unsigned short* __restrict__ wst) {
    const int gt = blockIdx.x * 256 + threadIdx.x;
    const int NT = 2048 * 256;
    // pack adj: 16.7M ints, 32 exact iterations
    for (int idx = gt; idx < NN * NN; idx += NT) {
        unsigned long long m = __ballot(adj[idx] > 0);
        if ((threadIdx.x & 63) == 0)
            *reinterpret_cast<unsigned long long*>(bits + ((idx >> 6) << 1)) = m;
    }
    // h -> bf16: 2M float4s, 4 exact iterations
    for (int idx = gt; idx < B_ * NN * DIN / 4; idx += NT) {
        float4 v = h4[idx];
        uint2 o;
        o.x = (uint32_t)f2bf(v.x) | ((uint32_t)f2bf(v.y) << 16);
        o.y = (uint32_t)f2bf(v.z) | ((uint32_t)f2bf(v.w) << 16);
        hb[idx] = o;
    }
    // Ws (B,DIN,DOUT) -> WsT (B,DOUT,DIN): 524288, 1 exact iteration
    for (int idx = gt; idx < B_ * DOUT * DIN; idx += NT) {
        int k = idx & (DIN - 1);
        int o = (idx >> 9) & (DOUT - 1);
        int b = idx >> 17;
        wst[idx] = f2bf(Ws[((size_t)b * DIN + k) * DOUT + o]);
    }
}

// ---------------- K1: WhT = (h@Ws)^T + fused e1/e2 -> factorized exp tables --------
__global__ __launch_bounds__(256) void k_gemm1(const unsigned short* __restrict__ hb,
                                               const unsigned short* __restrict__ wst,
                                               const float* __restrict__ a,
                                               unsigned short* __restrict__ wht,
                                               float2* __restrict__ x1t,
                                               float* __restrict__ y1t,
                                               float* __restrict__ y2t) {
    __shared__ unsigned short Ah[64 * 64];    // [n][k] swizzled rows (128B)
    __shared__ unsigned short Bw[256 * 64];   // [d][k] swizzled rows (128B)
    __shared__ float e1s[64], e2s[64];
    const int tid = threadIdx.x;
    const int w = tid >> 6, lane = tid & 63;
    const int l15 = lane & 15, lhi = lane >> 4;
    const int b = blockIdx.y;
    const int n0 = blockIdx.x * 64;
    const unsigned short* hrow = hb + ((size_t)b * NN + n0) * DIN;
    const unsigned short* wrow = wst + (size_t)b * DOUT * DIN;

    if (tid < 64) { e1s[tid] = 0.f; e2s[tid] = 0.f; }

    f32x4 acc[4][4] = {};

    for (int kt = 0; kt < DIN / 64; ++kt) {
        const int k0 = kt * 64;
        #pragma unroll
        for (int it = 0; it < 2; ++it) {     // stage A: 8KB
            int q = it * 256 + tid;
            int row = q >> 3, c = q & 7;
            const unsigned short* src = hrow + (size_t)row * DIN + k0 + 8 * (c ^ (row & 7));
            char* dst = reinterpret_cast<char*>(Ah) + it * 4096 + w * 1024;
            __builtin_amdgcn_global_load_lds((gconst_void*)src, (lds_void*)dst, 16, 0, 0);
        }
        #pragma unroll
        for (int it = 0; it < 8; ++it) {     // stage B: 32KB
            int q = it * 256 + tid;
            int row = q >> 3, c = q & 7;
            const unsigned short* src = wrow + (size_t)row * DIN + k0 + 8 * (c ^ (row & 7));
            char* dst = reinterpret_cast<char*>(Bw) + it * 4096 + w * 1024;
            __builtin_amdgcn_global_load_lds((gconst_void*)src, (lds_void*)dst, 16, 0, 0);
        }
        __syncthreads();
        #pragma unroll
        for (int kk = 0; kk < 2; ++kk) {
            short8 af[4], bfr[4];
            #pragma unroll
            for (int rf = 0; rf < 4; ++rf) {
                int row = rf * 16 + l15;
                int off = row * 128 + ((kk * 64 + lhi * 16) ^ ((row & 7) << 4));
                af[rf] = *reinterpret_cast<const short8*>(reinterpret_cast<const char*>(Ah) + off);
            }
            #pragma unroll
            for (int cf = 0; cf < 4; ++cf) {
                int row = w * 64 + cf * 16 + l15;
                int off = row * 128 + ((kk * 64 + lhi * 16) ^ ((row & 7) << 4));
                bfr[cf] = *reinterpret_cast<const short8*>(reinterpret_cast<const char*>(Bw) + off);
            }
            #pragma unroll
            for (int rf = 0; rf < 4; ++rf)
                #pragma unroll
                for (int cf = 0; cf < 4; ++cf)
                    acc[rf][cf] = __builtin_amdgcn_mfma_f32_16x16x32_bf16(af[rf], bfr[cf], acc[rf][cf], 0, 0, 0);
        }
        __syncthreads();
    }
    // WhT write (bf16, transposed)
    unsigned short* wb = wht + (size_t)b * DOUT * NN;
    #pragma unroll
    for (int rf = 0; rf < 4; ++rf) {
        #pragma unroll
        for (int cf = 0; cf < 4; ++cf) {
            int d = w * 64 + cf * 16 + l15;
            int m = n0 + rf * 16 + lhi * 4;
            uint2 pk;
            pk.x = (uint32_t)f2bf(acc[rf][cf][0]) | ((uint32_t)f2bf(acc[rf][cf][1]) << 16);
            pk.y = (uint32_t)f2bf(acc[rf][cf][2]) | ((uint32_t)f2bf(acc[rf][cf][3]) << 16);
            *reinterpret_cast<uint2*>(wb + (size_t)d * NN + m) = pk;
        }
    }
    // fused e1/e2 via shfl-reduce over the 16-lane fragment columns
    const float* ab = a + b * 2 * DOUT;
    float a1v[4], a2v[4];
    #pragma unroll
    for (int cf = 0; cf < 4; ++cf) {
        int d = w * 64 + cf * 16 + l15;
        a1v[cf] = ab[d];
        a2v[cf] = ab[DOUT + d];
    }
    #pragma unroll
    for (int rf = 0; rf < 4; ++rf) {
        #pragma unroll
        for (int j = 0; j < 4; ++j) {
            float p1 = 0.f, p2 = 0.f;
            #pragma unroll
            for (int cf = 0; cf < 4; ++cf) {
                p1 = fmaf(acc[rf][cf][j], a1v[cf], p1);
                p2 = fmaf(acc[rf][cf][j], a2v[cf], p2);
            }
            #pragma unroll
            for (int msk = 1; msk < 16; msk <<= 1) {
                p1 += __shfl_xor(p1, msk);
                p2 += __shfl_xor(p2, msk);
            }
            if (l15 == 0) {
                atomicAdd(&e1s[rf * 16 + lhi * 4 + j], p1);
                atomicAdd(&e2s[rf * 16 + lhi * 4 + j], p2);
            }
        }
    }
    __syncthreads();
    if (tid < 64) {
        float e1v = e1s[tid], e2v = e2s[tid];
        x1t[b * NN + n0 + tid] = float2{__expf(e1v), __expf(ALPHA_ * e1v)};
        y1t[b * NN + n0 + tid] = __expf(e2v);
        y2t[b * NN + n0 + tid] = __expf(ALPHA_ * e2v);
    }
}

// ---------------- K4: h' numerators, K-split x2; table-P (no exp in loop) ----------
// block 64n x 256d x half-K, 512 threads = 8 waves (2n x 4d), each 32n x 64d.
// P = max(X1[n]*Y1[m], X2[n]*Y2[m]) & adjmask — pure VALU (pk-f32 capable).
// P packed-words computed BEFORE the MFMA phase; only the ds_write sits between
// barriers. Staging/table pointers strength-reduced across tiles.
__global__ __launch_bounds__(512, 4) void k_attn(const unsigned short* __restrict__ wht,
                                                 const uint32_t* __restrict__ bits,
                                                 const float2* __restrict__ x1t,
                                                 const float* __restrict__ y1t,
                                                 const float* __restrict__ y2t,
                                                 float* __restrict__ out,
                                                 float* __restrict__ sums) {
    __shared__ unsigned short Bw[2 * 256 * 64];  // WhT tile dbuf, swizzled rows (64KB)
    __shared__ unsigned short Pt[64 * 64];       // P tile, single buffer (8KB)

    const int tid = threadIdx.x;
    const int w = tid >> 6, lane = tid & 63;
    const int l15 = lane & 15, lh4 = lane >> 4;
    const int wn = w >> 2, wd = w & 3;

    // XCD swizzle: 512 blocks; xcd g = (b, n-half); within: 32 n-chunks x 2 k-halves
    const int bid = blockIdx.x;
    const int wg = ((bid & 7) << 6) | (bid >> 3);
    const int g  = wg >> 6;            // == bid & 7 (XCD id)
    const int b  = g >> 1;
    const int n0 = ((g & 1) * 32 + (wg & 31)) << 6;
    const int T0 = ((wg >> 5) & 1) * 32;          // k-half: tiles [T0, T0+32)

    // P mapping: pr = row (0..63), pc = 8-m group (0..7)
    const int pr = tid >> 3, pc = tid & 7;
    const float2 xv = x1t[b * NN + n0 + pr];
    const float X1 = xv.x, X2 = xv.y;
    const unsigned short* wb = wht + (size_t)b * DOUT * NN;

    f32x4 acc[2][4] = {};
    f32x4 accs[2] = {};
    short8 ones;
    {
        union { short8 v; uint32_t u[4]; } ov;
        ov.u[0] = 0x3F803F80u; ov.u[1] = 0x3F803F80u;
        ov.u[2] = 0x3F803F80u; ov.u[3] = 0x3F803F80u;
        ones = ov.v;
    }

    // strength-reduced pointers
    const unsigned short* sp[4];
    #pragma unroll
    for (int it = 0; it < 4; ++it) {
        int q = it * 512 + tid;
        int row = q >> 3, c = q & 7;
        sp[it] = wb + (size_t)row * NN + T0 * 64 + 8 * (c ^ (row & 7));
    }
    const uint8_t* bp = reinterpret_cast<const uint8_t*>(bits) +
                        (size_t)(n0 + pr) * (NN / 8) + T0 * 8 + pc;
    const float4* y1p = reinterpret_cast<const float4*>(y1t + b * NN + T0 * 64 + pc * 8);
    const float4* y2p = reinterpret_cast<const float4*>(y2t + b * NN + T0 * 64 + pc * 8);

#define STAGE(BUF)                                                                     \
    {                                                                                  \
        _Pragma("unroll")                                                              \
        for (int it = 0; it < 4; ++it) {                                               \
            char* dst = reinterpret_cast<char*>(Bw) + (BUF) * 32768 + it * 8192 + w * 1024; \
            __builtin_amdgcn_global_load_lds((gconst_void*)sp[it], (lds_void*)dst, 16, 0, 0); \
            sp[it] += 64;                                                              \
        }                                                                              \
    }

#define P_MATH(BB, Y1A, Y1B, Y2A, Y2B, PKW)                                            \
    {                                                                                  \
        float v1[8] = {Y1A.x, Y1A.y, Y1A.z, Y1A.w, Y1B.x, Y1B.y, Y1B.z, Y1B.w};        \
        float v2[8] = {Y2A.x, Y2A.y, Y2A.z, Y2A.w, Y2B.x, Y2B.y, Y2B.z, Y2B.w};        \
        _Pragma("unroll")                                                              \
        for (int i = 0; i < 4; ++i) {                                                  \
            f32x2 pa = f32x2{v1[2 * i], v1[2 * i + 1]} * X1;                           \
            f32x2 pb = f32x2{v2[2 * i], v2[2 * i + 1]} * X2;                           \
            f32x2 pm = __builtin_elementwise_max(pa, pb);                              \
            union { __hip_bfloat162 h; uint32_t u; } cc;                               \
            cc.h = __float22bfloat162_rn(float2{pm.x, pm.y});                          \
            uint32_t b2 = ((BB) >> (2 * i)) & 3u;                                      \
            uint32_t mk = ((b2 & 1u) ? 0xFFFFu : 0u) | ((b2 & 2u) ? 0xFFFF0000u : 0u); \
            PKW[i] = cc.u & mk;                                                        \
        }                                                                              \
    }

#define PT_WRITE(PKW)                                                                  \
    {                                                                                  \
        uint4 qv; qv.x = PKW[0]; qv.y = PKW[1]; qv.z = PKW[2]; qv.w = PKW[3];          \
        *reinterpret_cast<uint4*>(reinterpret_cast<char*>(Pt) + pr * 128 +             \
                                  ((pc * 16) ^ ((pr & 7) << 4))) = qv;                 \
    }

#define MM(CUR)                                                                        \
    {                                                                                  \
        const char* bwb = reinterpret_cast<const char*>(Bw) + (CUR) * 32768;           \
        const char* ptb = reinterpret_cast<const char*>(Pt);                           \
        __builtin_amdgcn_s_setprio(1);                                                 \
        _Pragma("unroll")                                                              \
        for (int kk = 0; kk < 2; ++kk) {                                               \
            short8 af[2], bf[4];                                                       \
            _Pragma("unroll")                                                          \
            for (int rf = 0; rf < 2; ++rf) {                                           \
                int row = wn * 32 + rf * 16 + l15;                                     \
                int off = row * 128 + ((kk * 64 + lh4 * 16) ^ ((row & 7) << 4));       \
                af[rf] = *reinterpret_cast<const short8*>(ptb + off);                  \
            }                                                                          \
            _Pragma("unroll")                                                          \
            for (int cf = 0; cf < 4; ++cf) {                                           \
                int row = wd * 64 + cf * 16 + l15;                                     \
                int off = row * 128 + ((kk * 64 + lh4 * 16) ^ ((row & 7) << 4));       \
                bf[cf] = *reinterpret_cast<const short8*>(bwb + off);                  \
            }                                                                          \
            _Pragma("unroll")                                                          \
            for (int rf = 0; rf < 2; ++rf) {                                           \
                _Pragma("unroll")                                                      \
                for (int cf = 0; cf < 4; ++cf)                                         \
                    acc[rf][cf] = __builtin_amdgcn_mfma_f32_16x16x32_bf16(             \
                        af[rf], bf[cf], acc[rf][cf], 0, 0, 0);                         \
                accs[rf] = __builtin_amdgcn_mfma_f32_16x16x32_bf16(                    \
                    af[rf], ones, accs[rf], 0, 0, 0);                                  \
            }                                                                          \
        }                                                                              \
        __builtin_amdgcn_s_setprio(0);                                                 \
    }

    // ---- prologue: stage + P for first tile of this k-half ----
    STAGE(0)
    {
        uint32_t bb = *bp; bp += 8;
        float4 y1a = y1p[0], y1b = y1p[1]; y1p += 16;
        float4 y2a = y2p[0], y2b = y2p[1]; y2p += 16;
        uint32_t pkw[4];
        P_MATH(bb, y1a, y1b, y2a, y2b, pkw)
        PT_WRITE(pkw)
    }
    __syncthreads();

    // ---- main loop over 32 tiles ----
    for (int t = 0; t < 32; ++t) {
        const int cur = t & 1;
        uint32_t pkw[4];
        if (t < 31) {
            STAGE(cur ^ 1)
            uint32_t bb = *bp; bp += 8;
            float4 y1a = y1p[0], y1b = y1p[1]; y1p += 16;
            float4 y2a = y2p[0], y2b = y2p[1]; y2p += 16;
            P_MATH(bb, y1a, y1b, y2a, y2b, pkw)   // VALU, overlaps MM below
        }
        MM(cur)
        __syncthreads();                 // Pt reads done; staged buf drained
        if (t < 31) {
            PT_WRITE(pkw)                // only the write sits between barriers
            __syncthreads();
        }
    }
#undef STAGE
#undef P_MATH
#undef PT_WRITE
#undef MM

    // ---- epilogue: atomic-combine partial numerators and row sums ----
    #pragma unroll
    for (int rf = 0; rf < 2; ++rf) {
        #pragma unroll
        for (int cf = 0; cf < 4; ++cf) {
            int d = wd * 64 + cf * 16 + l15;
            #pragma unroll
            for (int j = 0; j < 4; ++j) {
                int nr = n0 + wn * 32 + rf * 16 + lh4 * 4 + j;
                atomicAdd(&out[((size_t)b * NN + nr) * DOUT + d], acc[rf][cf][j]);
            }
        }
    }
    if (wd == 0 && l15 == 0) {
        #pragma unroll
        for (int rf = 0; rf < 2; ++rf)
            #pragma unroll
            for (int j = 0; j < 4; ++j) {
                int nr = n0 + wn * 32 + rf * 16 + lh4 * 4 + j;
                atomicAdd(&sums[b * NN + nr], accs[rf][j]);
            }
    }
}

// ---------------- K5: finalize — out = ELU(out / sums[row]) in place ----------------
__global__ __launch_bounds__(256) void k_final(const float* __restrict__ sums,
                                               float* __restrict__ out) {
    int f4 = blockIdx.x * 256 + threadIdx.x;     // float4 index
    int row = f4 >> 6;                           // 64 float4 per (b,n) row
    float inv = 1.0f / sums[row];
    float4 v = reinterpret_cast<const float4*>(out)[f4];
    v.x *= inv; v.y *= inv; v.z *= inv; v.w *= inv;
    v.x = v.x > 0.f ? v.x : (__expf(v.x) - 1.f);
    v.y = v.y > 0.f ? v.y : (__expf(v.y) - 1.f);
    v.z = v.z > 0.f ? v.z : (__expf(v.z) - 1.f);
    v.w = v.w > 0.f ? v.w : (__expf(v.w) - 1.f);
    reinterpret_cast<float4*>(out)[f4] = v;
}

extern "C" void kernel_launch(void* const* d_in, const int* in_sizes, int n_in,
                              void* d_out, int out_size, void* d_ws, size_t ws_size,
                              hipStream_t stream) {
    (void)in_sizes; (void)n_in; (void)out_size; (void)ws_size;
    const float* h   = (const float*)d_in[0];
    const int*   adj = (const int*)d_in[1];
    const float* Ws  = (const float*)d_in[2];
    const float* a   = (const float*)d_in[3];
    float* out = (float*)d_out;

    char* ws = (char*)d_ws;
    unsigned short* hb  = (unsigned short*)(ws);              // 16,777,216 B
    unsigned short* wst = (unsigned short*)(ws + 16777216);   //  1,048,576 B
    unsigned short* wht = (unsigned short*)(ws + 17825792);   //  8,388,608 B
    float2* x1t = (float2*)(ws + 26214400);                   //    131,072 B
    float*  y1t = (float*)(ws + 26345472);                    //     65,536 B
    float*  y2t = (float*)(ws + 26411008);                    //     65,536 B
    uint32_t* bits = (uint32_t*)(ws + 26476544);              //  2,097,152 B
    float* sums = (float*)(ws + 28573696);                    //     65,536 B

    hipMemsetAsync(out, 0, (size_t)B_ * NN * DOUT * sizeof(float), stream);
    hipMemsetAsync(sums, 0, (size_t)B_ * NN * sizeof(float), stream);
    k_prep<<<dim3(2048), dim3(256), 0, stream>>>(adj, (const float4*)h, Ws,
                                                 bits, (uint2*)hb, wst);
    k_gemm1<<<dim3(NN / 64, B_), dim3(256), 0, stream>>>(hb, wst, a, wht, x1t, y1t, y2t);
    k_attn<<<dim3(512), dim3(512), 0, stream>>>(wht, bits, x1t, y1t, y2t, out, sums);
    k_final<<<dim3(B_ * NN * DOUT / 1024), dim3(256), 0, stream>>>(sums, out);
}